// Round 1
// baseline (1452.844 us; speedup 1.0000x reference)
//
#include <hip/hip_runtime.h>

// ---------------------------------------------------------------------------
// Stage 1: conv1 (11x11, Cin=1, Cout=32) + ReLU + maxpool 3x3 s2 ceil  (fused)
// x: (32,1,152,152)  w: (32,1,11,11)  b: (32)  out: (32,32,71,71)
// Block: 256 thr, one (b, co, 16x16-pooled-tile). Conv tile 33x33 in LDS.
// ---------------------------------------------------------------------------
__global__ __launch_bounds__(256) void conv1_pool_kernel(
    const float* __restrict__ x, const float* __restrict__ w,
    const float* __restrict__ bias, float* __restrict__ out)
{
    const int tile = blockIdx.x;          // 0..24  (5x5 tiles of 16x16 pooled)
    const int co   = blockIdx.y;          // 0..31
    const int b    = blockIdx.z;          // 0..31
    const int ty = tile / 5, tx = tile % 5;
    const int pr0 = ty * 16, pc0 = tx * 16;   // pooled-space origin
    const int cr0 = pr0 * 2, cc0 = pc0 * 2;   // conv-space origin (== input origin)

    __shared__ float in_s[43 * 43];
    __shared__ float w_s[121];
    __shared__ float conv_s[33 * 33];

    const int tid = threadIdx.x;
    if (tid < 121) w_s[tid] = w[co * 121 + tid];

    const float* xb = x + b * 152 * 152;
    for (int i = tid; i < 43 * 43; i += 256) {
        int r = i / 43, c = i % 43;
        int ir = cr0 + r, ic = cc0 + c;
        float v = 0.f;
        if (ir < 152 && ic < 152) v = xb[ir * 152 + ic];
        in_s[i] = v;
    }
    __syncthreads();

    const float bv = bias[co];
    for (int p = tid; p < 33 * 33; p += 256) {
        int pr = p / 33, pc = p % 33;
        float acc = 0.f;
        if (cr0 + pr < 142 && cc0 + pc < 142) {   // valid conv output range
            #pragma unroll
            for (int i = 0; i < 11; ++i) {
                const float* row = &in_s[(pr + i) * 43 + pc];
                #pragma unroll
                for (int j = 0; j < 11; ++j)
                    acc += row[j] * w_s[i * 11 + j];
            }
            acc = fmaxf(acc + bv, 0.f);
        }
        conv_s[p] = acc;   // 0 outside valid range; safe for max since relu>=0
    }
    __syncthreads();

    const int py = tid / 16, px = tid % 16;
    const int pr = pr0 + py, pc = pc0 + px;
    if (pr < 71 && pc < 71) {
        float m = 0.f;
        #pragma unroll
        for (int d = 0; d < 3; ++d) {
            const float* row = &conv_s[(py * 2 + d) * 33 + px * 2];
            m = fmaxf(m, fmaxf(fmaxf(row[0], row[1]), row[2]));
        }
        out[((b * 32 + co) * 71 + pr) * 71 + pc] = m;
    }
}

// ---------------------------------------------------------------------------
// Stage 2: conv2 (9x9, Cin=32, Cout=16) + ReLU
// in: (32,32,71,71)  w: (16,32,9,9)  out: (32,16,63,63)
// Block: 256 thr = (co 0..15, py 0..15); one (b, 16x16 output tile).
// ci staged in chunks of 4; per-thread 16-wide output row in registers.
// ---------------------------------------------------------------------------
__global__ __launch_bounds__(256) void conv2_kernel(
    const float* __restrict__ in, const float* __restrict__ w,
    const float* __restrict__ bias, float* __restrict__ out)
{
    const int tile = blockIdx.x;           // 0..15 -> 4x4 tiles
    const int b = blockIdx.y;
    const int ty = tile / 4, tx = tile % 4;
    const int oh0 = ty * 16, ow0 = tx * 16;

    __shared__ float in_s[4][24][25];      // +1 pad -> conflict-free
    __shared__ float w_s[16][324];

    const int tid = threadIdx.x;
    const int co = tid / 16;
    const int py = tid % 16;

    float acc[16];
    #pragma unroll
    for (int i = 0; i < 16; ++i) acc[i] = 0.f;

    for (int cc = 0; cc < 8; ++cc) {       // 8 chunks of 4 input channels
        for (int i = tid; i < 4 * 24 * 24; i += 256) {
            int ci = i / 576, r = (i / 24) % 24, c = i % 24;
            int ih = oh0 + r, iw = ow0 + c;
            float v = 0.f;
            if (ih < 71 && iw < 71)
                v = in[((b * 32 + cc * 4 + ci) * 71 + ih) * 71 + iw];
            in_s[ci][r][c] = v;
        }
        for (int i = tid; i < 16 * 324; i += 256) {
            int c2 = i / 324, t = i % 324;
            w_s[c2][t] = w[c2 * 2592 + cc * 324 + t];
        }
        __syncthreads();

        #pragma unroll 1
        for (int ci = 0; ci < 4; ++ci) {
            #pragma unroll 1
            for (int kh = 0; kh < 9; ++kh) {
                float rr[24];
                #pragma unroll
                for (int c = 0; c < 24; ++c) rr[c] = in_s[ci][py + kh][c];
                #pragma unroll
                for (int kw = 0; kw < 9; ++kw) {
                    float wv = w_s[co][ci * 81 + kh * 9 + kw];
                    #pragma unroll
                    for (int px = 0; px < 16; ++px)
                        acc[px] += rr[kw + px] * wv;
                }
            }
        }
        __syncthreads();
    }

    const int oh = oh0 + py;
    if (oh < 63) {
        const float bv = bias[co];
        #pragma unroll
        for (int px = 0; px < 16; ++px) {
            int ow = ow0 + px;
            if (ow < 63)
                out[((b * 16 + co) * 63 + oh) * 63 + ow] = fmaxf(acc[px] + bv, 0.f);
        }
    }
}

// ---------------------------------------------------------------------------
// Stages 3-5: locally-connected conv + ReLU (weights unique per position).
// Block per output position (oh,ow). 512 thr = (b=tid&31, co=tid>>5).
// Weights read from HBM exactly once (all 32 batches resident).
// K = 16*KS*KS staged into LDS in NCHUNK chunks of KC.
// w: (OH,OW,16,K)  bias: (16,OH,OW)
// ---------------------------------------------------------------------------
template<int KS, int STRIDE, int HIN, int WIN, int HOUT, int WOUT, int KC, int NCHUNK>
__global__ __launch_bounds__(512) void lc_kernel(
    const float* __restrict__ in, const float* __restrict__ w,
    const float* __restrict__ bias, float* __restrict__ out)
{
    constexpr int K = 16 * KS * KS;
    static_assert(KC * NCHUNK == K, "chunking must cover K");
    static_assert((KC % 4) == 0, "float4");

    const int pos = blockIdx.x;
    const int oh = pos / WOUT, ow = pos % WOUT;
    const int tid = threadIdx.x;
    const int b  = tid & 31;
    const int co = tid >> 5;

    __shared__ float patch[32][KC];

    float acc = 0.f;
    const float* wbase = w + (size_t)pos * 16 * K + co * K;

    for (int ch = 0; ch < NCHUNK; ++ch) {
        const int kb = ch * KC;
        for (int i = tid; i < 32 * KC; i += 512) {
            int bb = i / KC, k = i % KC;
            int kk = kb + k;
            int ci = kk / (KS * KS);
            int r  = kk % (KS * KS);
            int kh = r / KS, kw = r % KS;
            patch[bb][k] =
                in[((bb * 16 + ci) * HIN + oh * STRIDE + kh) * WIN + ow * STRIDE + kw];
        }
        __syncthreads();

        const float4* wp = reinterpret_cast<const float4*>(wbase + kb);
        const float4* pp = reinterpret_cast<const float4*>(&patch[b][0]);
        #pragma unroll 4
        for (int k4 = 0; k4 < KC / 4; ++k4) {
            float4 wv = wp[k4];
            float4 pv = pp[k4];
            acc += pv.x * wv.x + pv.y * wv.y + pv.z * wv.z + pv.w * wv.w;
        }
        __syncthreads();
    }

    acc += bias[co * (HOUT * WOUT) + pos];
    out[(b * 16 + co) * (HOUT * WOUT) + pos] = fmaxf(acc, 0.f);
}

// ---------------------------------------------------------------------------
// Stage 6: FC  (32,7056) @ (4096,7056)^T + b
// Block: 512 thr = (b, 16 outputs). Grid 256.
// ---------------------------------------------------------------------------
__global__ __launch_bounds__(512) void fc_kernel(
    const float* __restrict__ in, const float* __restrict__ w,
    const float* __restrict__ bias, float* __restrict__ out)
{
    constexpr int K = 7056, KC = 252, NCHUNK = 28;
    const int tid = threadIdx.x;
    const int b  = tid & 31;
    const int oi = tid >> 5;
    const int o = blockIdx.x * 16 + oi;

    __shared__ float patch[32][KC];
    float acc = 0.f;
    const float* wbase = w + (size_t)o * K;

    for (int ch = 0; ch < NCHUNK; ++ch) {
        const int kb = ch * KC;
        for (int i = tid; i < 32 * KC; i += 512) {
            int bb = i / KC, k = i % KC;
            patch[bb][k] = in[bb * K + kb + k];
        }
        __syncthreads();

        const float4* wp = reinterpret_cast<const float4*>(wbase + kb);
        const float4* pp = reinterpret_cast<const float4*>(&patch[b][0]);
        #pragma unroll 4
        for (int k4 = 0; k4 < KC / 4; ++k4) {
            float4 wv = wp[k4];
            float4 pv = pp[k4];
            acc += pv.x * wv.x + pv.y * wv.y + pv.z * wv.z + pv.w * wv.w;
        }
        __syncthreads();
    }

    out[b * 4096 + o] = acc + bias[o];
}

// ---------------------------------------------------------------------------
extern "C" void kernel_launch(void* const* d_in, const int* in_sizes, int n_in,
                              void* d_out, int out_size, void* d_ws, size_t ws_size,
                              hipStream_t stream) {
    const float* x    = (const float*)d_in[0];
    const float* c1w  = (const float*)d_in[1];
    const float* c1b  = (const float*)d_in[2];
    const float* c2w  = (const float*)d_in[3];
    const float* c2b  = (const float*)d_in[4];
    const float* lc1w = (const float*)d_in[5];
    const float* lc1b = (const float*)d_in[6];
    const float* lc2w = (const float*)d_in[7];
    const float* lc2b = (const float*)d_in[8];
    const float* lc3w = (const float*)d_in[9];
    const float* lc3b = (const float*)d_in[10];
    const float* fcw  = (const float*)d_in[11];
    const float* fcb  = (const float*)d_in[12];
    float* out = (float*)d_out;

    float* ws  = (float*)d_ws;
    float* h1p = ws;                 // 32*32*71*71 = 5,161,472
    float* h2  = h1p + 5161472;      // 32*16*63*63 = 2,032,128
    float* h3  = h2  + 2032128;      // 32*16*55*55 = 1,548,800
    float* h4  = h3  + 1548800;      // 32*16*25*25 =   320,000
    float* h5  = h4  + 320000;       // 32*16*21*21 =   225,792
                                     // total 9,288,192 floats = 37.2 MB

    conv1_pool_kernel<<<dim3(25, 32, 32), 256, 0, stream>>>(x, c1w, c1b, h1p);
    conv2_kernel<<<dim3(16, 32), 256, 0, stream>>>(h1p, c2w, c2b, h2);
    lc_kernel<9, 1, 63, 63, 55, 55, 324, 4><<<dim3(55 * 55), 512, 0, stream>>>(h2, lc1w, lc1b, h3);
    lc_kernel<7, 2, 55, 55, 25, 25, 196, 4><<<dim3(25 * 25), 512, 0, stream>>>(h3, lc2w, lc2b, h4);
    lc_kernel<5, 1, 25, 25, 21, 21, 100, 4><<<dim3(21 * 21), 512, 0, stream>>>(h4, lc3w, lc3b, h5);
    fc_kernel<<<dim3(256), 512, 0, stream>>>(h5, fcw, fcb, out);
}

// Round 2
// 1162.940 us; speedup vs baseline: 1.2493x; 1.2493x over previous
//
#include <hip/hip_runtime.h>

// ---------------------------------------------------------------------------
// Stage 1: conv1 (11x11, Cin=1, Cout=32) + ReLU + maxpool 3x3 s2 ceil  (fused)
// ---------------------------------------------------------------------------
__global__ __launch_bounds__(256) void conv1_pool_kernel(
    const float* __restrict__ x, const float* __restrict__ w,
    const float* __restrict__ bias, float* __restrict__ out)
{
    const int tile = blockIdx.x;          // 0..24
    const int co   = blockIdx.y;          // 0..31
    const int b    = blockIdx.z;          // 0..31
    const int ty = tile / 5, tx = tile % 5;
    const int pr0 = ty * 16, pc0 = tx * 16;
    const int cr0 = pr0 * 2, cc0 = pc0 * 2;

    __shared__ float in_s[43 * 43];
    __shared__ float w_s[121];
    __shared__ float conv_s[33 * 33];

    const int tid = threadIdx.x;
    if (tid < 121) w_s[tid] = w[co * 121 + tid];

    const float* xb = x + b * 152 * 152;
    for (int i = tid; i < 43 * 43; i += 256) {
        int r = i / 43, c = i % 43;
        int ir = cr0 + r, ic = cc0 + c;
        float v = 0.f;
        if (ir < 152 && ic < 152) v = xb[ir * 152 + ic];
        in_s[i] = v;
    }
    __syncthreads();

    const float bv = bias[co];
    for (int p = tid; p < 33 * 33; p += 256) {
        int pr = p / 33, pc = p % 33;
        float acc = 0.f;
        if (cr0 + pr < 142 && cc0 + pc < 142) {
            #pragma unroll
            for (int i = 0; i < 11; ++i) {
                const float* row = &in_s[(pr + i) * 43 + pc];
                #pragma unroll
                for (int j = 0; j < 11; ++j)
                    acc += row[j] * w_s[i * 11 + j];
            }
            acc = fmaxf(acc + bv, 0.f);
        }
        conv_s[p] = acc;
    }
    __syncthreads();

    const int py = tid / 16, px = tid % 16;
    const int pr = pr0 + py, pc = pc0 + px;
    if (pr < 71 && pc < 71) {
        float m = 0.f;
        #pragma unroll
        for (int d = 0; d < 3; ++d) {
            const float* row = &conv_s[(py * 2 + d) * 33 + px * 2];
            m = fmaxf(m, fmaxf(fmaxf(row[0], row[1]), row[2]));
        }
        out[((b * 32 + co) * 71 + pr) * 71 + pc] = m;
    }
}

// ---------------------------------------------------------------------------
// Stage 2: conv2 (9x9, Cin=32, Cout=16) + ReLU   (unchanged)
// ---------------------------------------------------------------------------
__global__ __launch_bounds__(256) void conv2_kernel(
    const float* __restrict__ in, const float* __restrict__ w,
    const float* __restrict__ bias, float* __restrict__ out)
{
    const int tile = blockIdx.x;
    const int b = blockIdx.y;
    const int ty = tile / 4, tx = tile % 4;
    const int oh0 = ty * 16, ow0 = tx * 16;

    __shared__ float in_s[4][24][25];
    __shared__ float w_s[16][324];

    const int tid = threadIdx.x;
    const int co = tid / 16;
    const int py = tid % 16;

    float acc[16];
    #pragma unroll
    for (int i = 0; i < 16; ++i) acc[i] = 0.f;

    for (int cc = 0; cc < 8; ++cc) {
        for (int i = tid; i < 4 * 24 * 24; i += 256) {
            int ci = i / 576, r = (i / 24) % 24, c = i % 24;
            int ih = oh0 + r, iw = ow0 + c;
            float v = 0.f;
            if (ih < 71 && iw < 71)
                v = in[((b * 32 + cc * 4 + ci) * 71 + ih) * 71 + iw];
            in_s[ci][r][c] = v;
        }
        for (int i = tid; i < 16 * 324; i += 256) {
            int c2 = i / 324, t = i % 324;
            w_s[c2][t] = w[c2 * 2592 + cc * 324 + t];
        }
        __syncthreads();

        #pragma unroll 1
        for (int ci = 0; ci < 4; ++ci) {
            #pragma unroll 1
            for (int kh = 0; kh < 9; ++kh) {
                float rr[24];
                #pragma unroll
                for (int c = 0; c < 24; ++c) rr[c] = in_s[ci][py + kh][c];
                #pragma unroll
                for (int kw = 0; kw < 9; ++kw) {
                    float wv = w_s[co][ci * 81 + kh * 9 + kw];
                    #pragma unroll
                    for (int px = 0; px < 16; ++px)
                        acc[px] += rr[kw + px] * wv;
                }
            }
        }
        __syncthreads();
    }

    const int oh = oh0 + py;
    if (oh < 63) {
        const float bv = bias[co];
        #pragma unroll
        for (int px = 0; px < 16; ++px) {
            int ow = ow0 + px;
            if (ow < 63)
                out[((b * 16 + co) * 63 + oh) * 63 + ow] = fmaxf(acc[px] + bv, 0.f);
        }
    }
}

// ---------------------------------------------------------------------------
// Stages 3-5 v2: locally-connected conv + ReLU.
// Block = 256 thr = 2 positions x (32 b x 4 co-quads). Per-thread 4 co accs.
// Weights: coalesced HBM -> LDS, consumed via broadcast (2 uniq addr/wave).
// Patch:   gathered once per position into swizzled LDS (conflict-free b128).
// Inner loop: 5 ds_read_b128 : 16 FMA  -> VALU-bound.
// ---------------------------------------------------------------------------
template<int KS, int STRIDE, int HIN, int WIN, int HOUT, int WOUT>
__global__ __launch_bounds__(256) void lc_v2_kernel(
    const float* __restrict__ in, const float* __restrict__ w,
    const float* __restrict__ bias, float* __restrict__ out)
{
    constexpr int K   = 16 * KS * KS;
    constexpr int K2  = KS * KS;
    constexpr int KC  = 72;                    // 18 float4 per chunk
    constexpr int NCH = (K + KC - 1) / KC;
    constexpr int HW  = HOUT * WOUT;

    __shared__ float4 patch_s[2][32][24];      // 18 used, swizzle pad -> 24.6 KB
    __shared__ float4 w_s[2][16][19];          // 18 used, +1 pad      ->  9.7 KB

    const int tid  = threadIdx.x;
    const int posi = tid >> 7;                 // which of the 2 positions
    const int t    = tid & 127;
    const int b    = t & 31;
    const int cp   = t >> 5;                   // 0..3 -> co = cp*4+j
    const int swz  = (b >> 2) & 7;

    const int pos0   = blockIdx.x * 2;
    const int mypos  = pos0 + posi;
    const bool myval = (mypos < HW);

    float acc0 = 0.f, acc1 = 0.f, acc2 = 0.f, acc3 = 0.f;

    for (int ch = 0; ch < NCH; ++ch) {
        const int kb = ch * KC;
        __syncthreads();                       // protect prev chunk reads

        // stage weights: 2 pos x 16 co x 18 f4 = 576 f4, coalesced
        for (int i4 = tid; i4 < 576; i4 += 256) {
            int pi  = i4 / 288;
            int rem = i4 - pi * 288;
            int co  = rem / 18;
            int x4  = rem - co * 18;
            int k   = kb + x4 * 4;
            int p   = pos0 + pi;
            float4 v = make_float4(0.f, 0.f, 0.f, 0.f);
            if (p < HW && k < K)
                v = *reinterpret_cast<const float4*>(w + ((size_t)p * 16 + co) * K + k);
            w_s[pi][co][x4] = v;
        }
        // stage patches: 2 pos x 32 b x 72 floats, scalar gather, swizzled
        for (int i = tid; i < 2 * 32 * KC; i += 256) {
            int pi  = i / (32 * KC);
            int rem = i - pi * (32 * KC);
            int bb  = rem / KC;
            int kk  = rem - bb * KC;
            int k   = kb + kk;
            int p   = pos0 + pi;
            float v = 0.f;
            if (p < HW && k < K) {
                int poh = p / WOUT, pw = p - poh * WOUT;
                int ci  = k / K2;
                int r   = k - ci * K2;
                int kh  = r / KS, kw = r - kh * KS;
                v = in[((bb * 16 + ci) * HIN + poh * STRIDE + kh) * WIN
                       + pw * STRIDE + kw];
            }
            int x4 = kk >> 2, j = kk & 3;
            int xs = x4 ^ ((bb >> 2) & 7);
            reinterpret_cast<float*>(&patch_s[pi][bb][xs])[j] = v;
        }
        __syncthreads();

        #pragma unroll
        for (int x4 = 0; x4 < 18; ++x4) {
            float4 pv = patch_s[posi][b][x4 ^ swz];
            float4 w0 = w_s[posi][cp * 4 + 0][x4];
            float4 w1 = w_s[posi][cp * 4 + 1][x4];
            float4 w2 = w_s[posi][cp * 4 + 2][x4];
            float4 w3 = w_s[posi][cp * 4 + 3][x4];
            acc0 += pv.x * w0.x + pv.y * w0.y + pv.z * w0.z + pv.w * w0.w;
            acc1 += pv.x * w1.x + pv.y * w1.y + pv.z * w1.z + pv.w * w1.w;
            acc2 += pv.x * w2.x + pv.y * w2.y + pv.z * w2.z + pv.w * w2.w;
            acc3 += pv.x * w3.x + pv.y * w3.y + pv.z * w3.z + pv.w * w3.w;
        }
    }

    if (myval) {
        const int cob = cp * 4;
        out[(b * 16 + cob + 0) * HW + mypos] = fmaxf(acc0 + bias[(cob + 0) * HW + mypos], 0.f);
        out[(b * 16 + cob + 1) * HW + mypos] = fmaxf(acc1 + bias[(cob + 1) * HW + mypos], 0.f);
        out[(b * 16 + cob + 2) * HW + mypos] = fmaxf(acc2 + bias[(cob + 2) * HW + mypos], 0.f);
        out[(b * 16 + cob + 3) * HW + mypos] = fmaxf(acc3 + bias[(cob + 3) * HW + mypos], 0.f);
    }
}

// ---------------------------------------------------------------------------
// Stage 6 v2: FC (32,7056)@(4096,7056)^T. K split 4 ways across blocks.
// Block = 256 thr = 32 b x 8 o-quads, o-tile 32. Grid (128, 4).
// Partials -> ws, reduced by fc_reduce_kernel.
// ---------------------------------------------------------------------------
__global__ __launch_bounds__(256) void fc_v2_kernel(
    const float* __restrict__ in, const float* __restrict__ w,
    float* __restrict__ part)
{
    constexpr int K  = 7056;
    constexpr int KR = 1764;                   // per-split range
    constexpr int KC = 144;                    // 36 f4
    constexpr int NCH = (KR + KC - 1) / KC;    // 13

    __shared__ float4 patch_s[32][40];         // 36 used, swizzle pad -> 20.5 KB
    __shared__ float4 w_s[32][37];             // 36 used, +1 pad      -> 18.9 KB

    const int tid = threadIdx.x;
    const int b   = tid & 31;
    const int op  = tid >> 5;                  // 0..7
    const int swz = (b >> 2) & 7;
    const int oblk = blockIdx.x;               // 0..127
    const int ks   = blockIdx.y;               // 0..3
    const int kbeg = ks * KR;
    const int klim = kbeg + KR;

    float acc0 = 0.f, acc1 = 0.f, acc2 = 0.f, acc3 = 0.f;

    for (int ch = 0; ch < NCH; ++ch) {
        const int kb = kbeg + ch * KC;
        __syncthreads();

        for (int i4 = tid; i4 < 32 * 36; i4 += 256) {
            int bb = i4 / 36, x4 = i4 - bb * 36;
            int k = kb + x4 * 4;
            float4 v = make_float4(0.f, 0.f, 0.f, 0.f);
            if (k < klim)
                v = *reinterpret_cast<const float4*>(in + bb * K + k);
            patch_s[bb][x4 ^ ((bb >> 2) & 7)] = v;
        }
        for (int i4 = tid; i4 < 32 * 36; i4 += 256) {
            int oi = i4 / 36, x4 = i4 - oi * 36;
            int k = kb + x4 * 4;
            float4 v = make_float4(0.f, 0.f, 0.f, 0.f);
            if (k < klim)
                v = *reinterpret_cast<const float4*>(w + (size_t)(oblk * 32 + oi) * K + k);
            w_s[oi][x4] = v;
        }
        __syncthreads();

        #pragma unroll
        for (int x4 = 0; x4 < 36; ++x4) {
            float4 pv = patch_s[b][x4 ^ swz];
            float4 w0 = w_s[op * 4 + 0][x4];
            float4 w1 = w_s[op * 4 + 1][x4];
            float4 w2 = w_s[op * 4 + 2][x4];
            float4 w3 = w_s[op * 4 + 3][x4];
            acc0 += pv.x * w0.x + pv.y * w0.y + pv.z * w0.z + pv.w * w0.w;
            acc1 += pv.x * w1.x + pv.y * w1.y + pv.z * w1.z + pv.w * w1.w;
            acc2 += pv.x * w2.x + pv.y * w2.y + pv.z * w2.z + pv.w * w2.w;
            acc3 += pv.x * w3.x + pv.y * w3.y + pv.z * w3.z + pv.w * w3.w;
        }
    }

    float4 r = make_float4(acc0, acc1, acc2, acc3);
    *reinterpret_cast<float4*>(part + (size_t)(ks * 32 + b) * 4096 + oblk * 32 + op * 4) = r;
}

__global__ __launch_bounds__(256) void fc_reduce_kernel(
    const float* __restrict__ part, const float* __restrict__ bias,
    float* __restrict__ out)
{
    int i4 = blockIdx.x * 256 + threadIdx.x;   // 32768 float4 outputs
    if (i4 >= 32768) return;
    int b = i4 >> 10, o4 = i4 & 1023;
    const size_t stride = (size_t)32 * 4096;
    const float* base = part + (size_t)b * 4096 + o4 * 4;
    float4 s0 = *reinterpret_cast<const float4*>(base);
    float4 s1 = *reinterpret_cast<const float4*>(base + stride);
    float4 s2 = *reinterpret_cast<const float4*>(base + 2 * stride);
    float4 s3 = *reinterpret_cast<const float4*>(base + 3 * stride);
    float4 bv = *reinterpret_cast<const float4*>(bias + o4 * 4);
    float4 r;
    r.x = s0.x + s1.x + s2.x + s3.x + bv.x;
    r.y = s0.y + s1.y + s2.y + s3.y + bv.y;
    r.z = s0.z + s1.z + s2.z + s3.z + bv.z;
    r.w = s0.w + s1.w + s2.w + s3.w + bv.w;
    *reinterpret_cast<float4*>(out + b * 4096 + o4 * 4) = r;
}

// ---------------------------------------------------------------------------
extern "C" void kernel_launch(void* const* d_in, const int* in_sizes, int n_in,
                              void* d_out, int out_size, void* d_ws, size_t ws_size,
                              hipStream_t stream) {
    const float* x    = (const float*)d_in[0];
    const float* c1w  = (const float*)d_in[1];
    const float* c1b  = (const float*)d_in[2];
    const float* c2w  = (const float*)d_in[3];
    const float* c2b  = (const float*)d_in[4];
    const float* lc1w = (const float*)d_in[5];
    const float* lc1b = (const float*)d_in[6];
    const float* lc2w = (const float*)d_in[7];
    const float* lc2b = (const float*)d_in[8];
    const float* lc3w = (const float*)d_in[9];
    const float* lc3b = (const float*)d_in[10];
    const float* fcw  = (const float*)d_in[11];
    const float* fcb  = (const float*)d_in[12];
    float* out = (float*)d_out;

    float* ws  = (float*)d_ws;
    float* h1p = ws;                 // 32*32*71*71 = 5,161,472
    float* h2  = h1p + 5161472;      // 32*16*63*63 = 2,032,128
    float* h3  = h2  + 2032128;      // 32*16*55*55 = 1,548,800
    float* h4  = h3  + 1548800;      // 32*16*25*25 =   320,000
    float* h5  = h4  + 320000;       // 32*16*21*21 =   225,792
    float* fc_part = h1p;            // reuse: conv1 output dead by fc time (524,288 floats)

    conv1_pool_kernel<<<dim3(25, 32, 32), 256, 0, stream>>>(x, c1w, c1b, h1p);
    conv2_kernel<<<dim3(16, 32), 256, 0, stream>>>(h1p, c2w, c2b, h2);
    lc_v2_kernel<9, 1, 63, 63, 55, 55><<<dim3((55 * 55 + 1) / 2), 256, 0, stream>>>(h2, lc1w, lc1b, h3);
    lc_v2_kernel<7, 2, 55, 55, 25, 25><<<dim3((25 * 25 + 1) / 2), 256, 0, stream>>>(h3, lc2w, lc2b, h4);
    lc_v2_kernel<5, 1, 25, 25, 21, 21><<<dim3((21 * 21 + 1) / 2), 256, 0, stream>>>(h4, lc3w, lc3b, h5);
    fc_v2_kernel<<<dim3(128, 4), 256, 0, stream>>>(h5, fcw, fc_part);
    fc_reduce_kernel<<<dim3(128), 256, 0, stream>>>(fc_part, fcb, out);
}

// Round 4
// 1020.392 us; speedup vs baseline: 1.4238x; 1.1397x over previous
//
#include <hip/hip_runtime.h>

// ---------------------------------------------------------------------------
// Stage 1: conv1 (11x11, Cin=1, Cout=32) + ReLU + maxpool 3x3 s2 ceil  (fused)
// ---------------------------------------------------------------------------
__global__ __launch_bounds__(256) void conv1_pool_kernel(
    const float* __restrict__ x, const float* __restrict__ w,
    const float* __restrict__ bias, float* __restrict__ out)
{
    const int tile = blockIdx.x;          // 0..24
    const int co   = blockIdx.y;          // 0..31
    const int b    = blockIdx.z;          // 0..31
    const int ty = tile / 5, tx = tile % 5;
    const int pr0 = ty * 16, pc0 = tx * 16;
    const int cr0 = pr0 * 2, cc0 = pc0 * 2;

    __shared__ float in_s[43 * 43];
    __shared__ float w_s[121];
    __shared__ float conv_s[33 * 33];

    const int tid = threadIdx.x;
    if (tid < 121) w_s[tid] = w[co * 121 + tid];

    const float* xb = x + b * 152 * 152;
    for (int i = tid; i < 43 * 43; i += 256) {
        int r = i / 43, c = i % 43;
        int ir = cr0 + r, ic = cc0 + c;
        float v = 0.f;
        if (ir < 152 && ic < 152) v = xb[ir * 152 + ic];
        in_s[i] = v;
    }
    __syncthreads();

    const float bv = bias[co];
    for (int p = tid; p < 33 * 33; p += 256) {
        int pr = p / 33, pc = p % 33;
        float acc = 0.f;
        if (cr0 + pr < 142 && cc0 + pc < 142) {
            #pragma unroll
            for (int i = 0; i < 11; ++i) {
                const float* row = &in_s[(pr + i) * 43 + pc];
                #pragma unroll
                for (int j = 0; j < 11; ++j)
                    acc += row[j] * w_s[i * 11 + j];
            }
            acc = fmaxf(acc + bv, 0.f);
        }
        conv_s[p] = acc;
    }
    __syncthreads();

    const int py = tid / 16, px = tid % 16;
    const int pr = pr0 + py, pc = pc0 + px;
    if (pr < 71 && pc < 71) {
        float m = 0.f;
        #pragma unroll
        for (int d = 0; d < 3; ++d) {
            const float* row = &conv_s[(py * 2 + d) * 33 + px * 2];
            m = fmaxf(m, fmaxf(fmaxf(row[0], row[1]), row[2]));
        }
        out[((b * 32 + co) * 71 + pr) * 71 + pc] = m;
    }
}

// ---------------------------------------------------------------------------
// Stage 2: conv2 (9x9, Cin=32, Cout=16) + ReLU   (unchanged)
// ---------------------------------------------------------------------------
__global__ __launch_bounds__(256) void conv2_kernel(
    const float* __restrict__ in, const float* __restrict__ w,
    const float* __restrict__ bias, float* __restrict__ out)
{
    const int tile = blockIdx.x;
    const int b = blockIdx.y;
    const int ty = tile / 4, tx = tile % 4;
    const int oh0 = ty * 16, ow0 = tx * 16;

    __shared__ float in_s[4][24][25];
    __shared__ float w_s[16][324];

    const int tid = threadIdx.x;
    const int co = tid / 16;
    const int py = tid % 16;

    float acc[16];
    #pragma unroll
    for (int i = 0; i < 16; ++i) acc[i] = 0.f;

    for (int cc = 0; cc < 8; ++cc) {
        for (int i = tid; i < 4 * 24 * 24; i += 256) {
            int ci = i / 576, r = (i / 24) % 24, c = i % 24;
            int ih = oh0 + r, iw = ow0 + c;
            float v = 0.f;
            if (ih < 71 && iw < 71)
                v = in[((b * 32 + cc * 4 + ci) * 71 + ih) * 71 + iw];
            in_s[ci][r][c] = v;
        }
        for (int i = tid; i < 16 * 324; i += 256) {
            int c2 = i / 324, t = i % 324;
            w_s[c2][t] = w[c2 * 2592 + cc * 324 + t];
        }
        __syncthreads();

        #pragma unroll 1
        for (int ci = 0; ci < 4; ++ci) {
            #pragma unroll 1
            for (int kh = 0; kh < 9; ++kh) {
                float rr[24];
                #pragma unroll
                for (int c = 0; c < 24; ++c) rr[c] = in_s[ci][py + kh][c];
                #pragma unroll
                for (int kw = 0; kw < 9; ++kw) {
                    float wv = w_s[co][ci * 81 + kh * 9 + kw];
                    #pragma unroll
                    for (int px = 0; px < 16; ++px)
                        acc[px] += rr[kw + px] * wv;
                }
            }
        }
        __syncthreads();
    }

    const int oh = oh0 + py;
    if (oh < 63) {
        const float bv = bias[co];
        #pragma unroll
        for (int px = 0; px < 16; ++px) {
            int ow = ow0 + px;
            if (ow < 63)
                out[((b * 16 + co) * 63 + oh) * 63 + ow] = fmaxf(acc[px] + bv, 0.f);
        }
    }
}

// ---------------------------------------------------------------------------
// Stages 3-5 v3: locally-connected conv + ReLU.
// Block per position. 256 thr = bg(2) x cog(4) x kl(32).
// Weights: HBM -> registers directly (coalesced, no LDS round-trip),
//          reused across 16 b-iterations from regs.
// Patch:   staged per 128-k pass into LDS (row stride 132 floats -> rows
//          rotate banks; consumption is contiguous 512B per 32 lanes ->
//          conflict-free). Offset table base[k] built once per block kills
//          per-element div/mod in the gather.
// Inner:   per b-iter: 1 ds_read_b128 + 16 v_fmac  (FMA-dominated issue).
// Epilogue: shfl_xor reduce over the 32 kl lanes.
// ---------------------------------------------------------------------------
template<int KS, int STRIDE, int HIN, int WIN, int HOUT, int WOUT>
__global__ __launch_bounds__(256, 4) void lc_v3_kernel(
    const float* __restrict__ in, const float* __restrict__ w,
    const float* __restrict__ bias, float* __restrict__ out)
{
    constexpr int K     = 16 * KS * KS;
    constexpr int NPASS = (K + 127) / 128;
    constexpr int KPAD  = NPASS * 128;
    constexpr int HW    = HOUT * WOUT;
    constexpr int CHW   = 16 * HIN * WIN;
    constexpr int ROWF  = 132;             // floats per patch row (528B % 128B = 16)

    __shared__ float patch_s[32 * ROWF];   // 16,896 B
    __shared__ int   base_s[KPAD];         // <= 5,632 B

    const int tid = threadIdx.x;
    const int pos = blockIdx.x;
    const int oh = pos / WOUT, ow = pos % WOUT;
    const int posoff = (oh * STRIDE) * WIN + ow * STRIDE;

    // position-independent gather-offset table (built once)
    for (int k = tid; k < KPAD; k += 256) {
        int v = 0;
        if (k < K) {
            int ci = k / (KS * KS);
            int r  = k - ci * (KS * KS);
            int kh = r / KS, kw = r - kh * KS;
            v = ci * (HIN * WIN) + kh * WIN + kw;
        }
        base_s[k] = v;
    }

    const int kl  = tid & 31;              // k-lane
    const int cog = (tid >> 5) & 3;        // co group: co = cog*4 + cj
    const int bg  = tid >> 7;              // batch half
    const int b0  = bg * 16;

    // staging role: thread stages 16 consecutive floats of one batch row
    const int sb = tid >> 3;               // 0..31
    const int si = (tid & 7) * 16;         // 0,16,...,112
    const float* inb = in + sb * CHW + posoff;

    const float* wbase = w + (size_t)pos * 16 * K;

    float acc[16][4];
    #pragma unroll
    for (int i = 0; i < 16; ++i)
        #pragma unroll
        for (int j = 0; j < 4; ++j) acc[i][j] = 0.f;

    #pragma unroll 1
    for (int ps = 0; ps < NPASS; ++ps) {
        const int kb = ps * 128;

        // weight fragments -> registers (coalesced 512B per co row per 32 lanes)
        const int kw4 = kb + kl * 4;
        float4 wv[4];
        #pragma unroll
        for (int cj = 0; cj < 4; ++cj) {
            if (kw4 < K)
                wv[cj] = *reinterpret_cast<const float4*>(
                    wbase + (size_t)(cog * 4 + cj) * K + kw4);
            else
                wv[cj] = make_float4(0.f, 0.f, 0.f, 0.f);
        }

        __syncthreads();   // previous pass consumption done

        // stage patch chunk: 16 elements per thread, offsets from table
        float tmp[16];
        #pragma unroll
        for (int j = 0; j < 16; ++j)
            tmp[j] = inb[base_s[kb + si + j]];
        #pragma unroll
        for (int j4 = 0; j4 < 4; ++j4) {
            *reinterpret_cast<float4*>(&patch_s[sb * ROWF + si + j4 * 4]) =
                make_float4(tmp[j4 * 4], tmp[j4 * 4 + 1],
                            tmp[j4 * 4 + 2], tmp[j4 * 4 + 3]);
        }
        __syncthreads();

        // compute: 16 b-iters x (1 ds_read_b128 + 16 FMA)
        #pragma unroll
        for (int bi = 0; bi < 16; ++bi) {
            float4 pv = *reinterpret_cast<const float4*>(
                &patch_s[(b0 + bi) * ROWF + kl * 4]);
            #pragma unroll
            for (int cj = 0; cj < 4; ++cj) {
                acc[bi][cj] += pv.x * wv[cj].x + pv.y * wv[cj].y
                             + pv.z * wv[cj].z + pv.w * wv[cj].w;
            }
        }
    }

    // reduce over kl lanes (masks 1..16 stay within 32-lane halves)
    #pragma unroll
    for (int bi = 0; bi < 16; ++bi)
        #pragma unroll
        for (int cj = 0; cj < 4; ++cj) {
            float v = acc[bi][cj];
            v += __shfl_xor(v, 1);
            v += __shfl_xor(v, 2);
            v += __shfl_xor(v, 4);
            v += __shfl_xor(v, 8);
            v += __shfl_xor(v, 16);
            acc[bi][cj] = v;
        }

    if (kl == 0) {
        float bv[4];
        #pragma unroll
        for (int cj = 0; cj < 4; ++cj)
            bv[cj] = bias[(cog * 4 + cj) * HW + pos];
        #pragma unroll
        for (int bi = 0; bi < 16; ++bi)
            #pragma unroll
            for (int cj = 0; cj < 4; ++cj) {
                int b = b0 + bi, co = cog * 4 + cj;
                out[(b * 16 + co) * HW + pos] = fmaxf(acc[bi][cj] + bv[cj], 0.f);
            }
    }
}

// ---------------------------------------------------------------------------
// Stage 6 v2: FC (32,7056)@(4096,7056)^T. K split 4 ways across blocks.
// ---------------------------------------------------------------------------
__global__ __launch_bounds__(256) void fc_v2_kernel(
    const float* __restrict__ in, const float* __restrict__ w,
    float* __restrict__ part)
{
    constexpr int K  = 7056;
    constexpr int KR = 1764;
    constexpr int KC = 144;
    constexpr int NCH = (KR + KC - 1) / KC;

    __shared__ float4 patch_s[32][40];
    __shared__ float4 w_s[32][37];

    const int tid = threadIdx.x;
    const int b   = tid & 31;
    const int op  = tid >> 5;
    const int swz = (b >> 2) & 7;
    const int oblk = blockIdx.x;
    const int ks   = blockIdx.y;
    const int kbeg = ks * KR;
    const int klim = kbeg + KR;

    float acc0 = 0.f, acc1 = 0.f, acc2 = 0.f, acc3 = 0.f;

    for (int ch = 0; ch < NCH; ++ch) {
        const int kb = kbeg + ch * KC;
        __syncthreads();

        for (int i4 = tid; i4 < 32 * 36; i4 += 256) {
            int bb = i4 / 36, x4 = i4 - bb * 36;
            int k = kb + x4 * 4;
            float4 v = make_float4(0.f, 0.f, 0.f, 0.f);
            if (k < klim)
                v = *reinterpret_cast<const float4*>(in + bb * K + k);
            patch_s[bb][x4 ^ ((bb >> 2) & 7)] = v;
        }
        for (int i4 = tid; i4 < 32 * 36; i4 += 256) {
            int oi = i4 / 36, x4 = i4 - oi * 36;
            int k = kb + x4 * 4;
            float4 v = make_float4(0.f, 0.f, 0.f, 0.f);
            if (k < klim)
                v = *reinterpret_cast<const float4*>(w + (size_t)(oblk * 32 + oi) * K + k);
            w_s[oi][x4] = v;
        }
        __syncthreads();

        #pragma unroll
        for (int x4 = 0; x4 < 36; ++x4) {
            float4 pv = patch_s[b][x4 ^ swz];
            float4 w0 = w_s[op * 4 + 0][x4];
            float4 w1 = w_s[op * 4 + 1][x4];
            float4 w2 = w_s[op * 4 + 2][x4];
            float4 w3 = w_s[op * 4 + 3][x4];
            acc0 += pv.x * w0.x + pv.y * w0.y + pv.z * w0.z + pv.w * w0.w;
            acc1 += pv.x * w1.x + pv.y * w1.y + pv.z * w1.z + pv.w * w1.w;
            acc2 += pv.x * w2.x + pv.y * w2.y + pv.z * w2.z + pv.w * w2.w;
            acc3 += pv.x * w3.x + pv.y * w3.y + pv.z * w3.z + pv.w * w3.w;
        }
    }

    float4 r = make_float4(acc0, acc1, acc2, acc3);
    *reinterpret_cast<float4*>(part + (size_t)(ks * 32 + b) * 4096 + oblk * 32 + op * 4) = r;
}

__global__ __launch_bounds__(256) void fc_reduce_kernel(
    const float* __restrict__ part, const float* __restrict__ bias,
    float* __restrict__ out)
{
    int i4 = blockIdx.x * 256 + threadIdx.x;
    if (i4 >= 32768) return;
    int b = i4 >> 10, o4 = i4 & 1023;
    const size_t stride = (size_t)32 * 4096;
    const float* base = part + (size_t)b * 4096 + o4 * 4;
    float4 s0 = *reinterpret_cast<const float4*>(base);
    float4 s1 = *reinterpret_cast<const float4*>(base + stride);
    float4 s2 = *reinterpret_cast<const float4*>(base + 2 * stride);
    float4 s3 = *reinterpret_cast<const float4*>(base + 3 * stride);
    float4 bv = *reinterpret_cast<const float4*>(bias + o4 * 4);
    float4 r;
    r.x = s0.x + s1.x + s2.x + s3.x + bv.x;
    r.y = s0.y + s1.y + s2.y + s3.y + bv.y;
    r.z = s0.z + s1.z + s2.z + s3.z + bv.z;
    r.w = s0.w + s1.w + s2.w + s3.w + bv.w;
    *reinterpret_cast<float4*>(out + b * 4096 + o4 * 4) = r;
}

// ---------------------------------------------------------------------------
extern "C" void kernel_launch(void* const* d_in, const int* in_sizes, int n_in,
                              void* d_out, int out_size, void* d_ws, size_t ws_size,
                              hipStream_t stream) {
    const float* x    = (const float*)d_in[0];
    const float* c1w  = (const float*)d_in[1];
    const float* c1b  = (const float*)d_in[2];
    const float* c2w  = (const float*)d_in[3];
    const float* c2b  = (const float*)d_in[4];
    const float* lc1w = (const float*)d_in[5];
    const float* lc1b = (const float*)d_in[6];
    const float* lc2w = (const float*)d_in[7];
    const float* lc2b = (const float*)d_in[8];
    const float* lc3w = (const float*)d_in[9];
    const float* lc3b = (const float*)d_in[10];
    const float* fcw  = (const float*)d_in[11];
    const float* fcb  = (const float*)d_in[12];
    float* out = (float*)d_out;

    float* ws  = (float*)d_ws;
    float* h1p = ws;                 // 32*32*71*71 = 5,161,472
    float* h2  = h1p + 5161472;      // 32*16*63*63 = 2,032,128
    float* h3  = h2  + 2032128;      // 32*16*55*55 = 1,548,800
    float* h4  = h3  + 1548800;      // 32*16*25*25 =   320,000
    float* h5  = h4  + 320000;       // 32*16*21*21 =   225,792
    float* fc_part = h1p;            // conv1 output dead by fc time

    conv1_pool_kernel<<<dim3(25, 32, 32), 256, 0, stream>>>(x, c1w, c1b, h1p);
    conv2_kernel<<<dim3(16, 32), 256, 0, stream>>>(h1p, c2w, c2b, h2);
    lc_v3_kernel<9, 1, 63, 63, 55, 55><<<dim3(55 * 55), 256, 0, stream>>>(h2, lc1w, lc1b, h3);
    lc_v3_kernel<7, 2, 55, 55, 25, 25><<<dim3(25 * 25), 256, 0, stream>>>(h3, lc2w, lc2b, h4);
    lc_v3_kernel<5, 1, 25, 25, 21, 21><<<dim3(21 * 21), 256, 0, stream>>>(h4, lc3w, lc3b, h5);
    fc_v2_kernel<<<dim3(128, 4), 256, 0, stream>>>(h5, fcw, fc_part);
    fc_reduce_kernel<<<dim3(128), 256, 0, stream>>>(fc_part, fcb, out);
}

// Round 5
// 785.969 us; speedup vs baseline: 1.8485x; 1.2983x over previous
//
#include <hip/hip_runtime.h>

// ---------------------------------------------------------------------------
// Stage 1 v2: conv1 (11x11, Cin=1, Cout=32) + ReLU + maxpool 3x3 s2 ceil.
// Grid (25 tiles, 4 co-groups, 32 b), block 256.
// Input tile 43x44 staged once, shared by 8 co. Row-task per lane: one
// 33-wide conv row in acc[33], input rows read as 11 x ds_read_b128
// (8 unique rows/wave -> start banks 12*row mod 32 tile all 32 banks ->
// conflict-free). Horizontal pool in registers; only 16 floats/row to LDS.
// ---------------------------------------------------------------------------
__global__ __launch_bounds__(256, 4) void conv1_pool_v2_kernel(
    const float* __restrict__ x, const float* __restrict__ w,
    const float* __restrict__ bias, float* __restrict__ out)
{
    const int tile = blockIdx.x;          // 0..24
    const int cog  = blockIdx.y;          // 0..3  (8 couts each)
    const int b    = blockIdx.z;          // 0..31
    const int ty = tile / 5, tx = tile % 5;
    const int pr0 = ty * 16, pc0 = tx * 16;   // pooled origin
    const int cr0 = pr0 * 2, cc0 = pc0 * 2;   // conv origin

    __shared__ float in_s[43 * 44];           // 7.6 KB
    __shared__ float w_s[8][121];             // 3.9 KB
    __shared__ float hp_s[33][8][17];         // 17.9 KB (h-pooled rows)

    const int tid = threadIdx.x;

    // stage input tile once (zero-pad beyond 152)
    const float* xb = x + b * 152 * 152;
    for (int i = tid; i < 43 * 44; i += 256) {
        int r = i / 44, c = i - r * 44;
        int ir = cr0 + r, ic = cc0 + c;
        in_s[i] = (ir < 152 && ic < 152) ? xb[ir * 152 + ic] : 0.f;
    }
    // stage this co-group's weights
    for (int i = tid; i < 8 * 121; i += 256) {
        int co = i / 121, k = i - co * 121;
        w_s[co][k] = w[(cog * 8 + co) * 121 + k];
    }
    __syncthreads();

    // conv + relu + horizontal pool: 264 row-tasks = 8 co x 33 rows
    for (int task = tid; task < 264; task += 256) {
        const int co  = task & 7;
        const int row = task >> 3;
        float hmax[16];
        if (cr0 + row < 142) {
            float acc[33];
            #pragma unroll
            for (int px = 0; px < 33; ++px) acc[px] = 0.f;
            #pragma unroll 1
            for (int kh = 0; kh < 11; ++kh) {
                float4 rq[11];
                #pragma unroll
                for (int j = 0; j < 11; ++j)
                    rq[j] = *reinterpret_cast<const float4*>(
                        &in_s[(row + kh) * 44 + j * 4]);
                const float* rr = reinterpret_cast<const float*>(rq);
                #pragma unroll
                for (int kw = 0; kw < 11; ++kw) {
                    float wv = w_s[co][kh * 11 + kw];
                    #pragma unroll
                    for (int px = 0; px < 33; ++px)
                        acc[px] += rr[px + kw] * wv;
                }
            }
            const float bv = bias[cog * 8 + co];
            #pragma unroll
            for (int px = 0; px < 33; ++px) {
                float v = fmaxf(acc[px] + bv, 0.f);
                acc[px] = (cc0 + px < 142) ? v : 0.f;   // col pad = 0, safe (relu>=0)
            }
            #pragma unroll
            for (int pc = 0; pc < 16; ++pc)
                hmax[pc] = fmaxf(fmaxf(acc[2 * pc], acc[2 * pc + 1]), acc[2 * pc + 2]);
        } else {
            #pragma unroll
            for (int pc = 0; pc < 16; ++pc) hmax[pc] = 0.f;   // row pad
        }
        #pragma unroll
        for (int pc = 0; pc < 16; ++pc) hp_s[row][co][pc] = hmax[pc];
    }
    __syncthreads();

    // vertical pool + coalesced store: 8 co x 16 x 16 pooled outputs
    for (int t = tid; t < 2048; t += 256) {
        int co = t >> 8, r = t & 255;
        int ppy = r >> 4, ppc = r & 15;
        float v = fmaxf(fmaxf(hp_s[2 * ppy][co][ppc], hp_s[2 * ppy + 1][co][ppc]),
                        hp_s[2 * ppy + 2][co][ppc]);
        int pr = pr0 + ppy, pc = pc0 + ppc;
        if (pr < 71 && pc < 71)
            out[((b * 32 + cog * 8 + co) * 71 + pr) * 71 + pc] = v;
    }
}

// ---------------------------------------------------------------------------
// Stage 2: conv2 (9x9, Cin=32, Cout=16) + ReLU   (unchanged)
// ---------------------------------------------------------------------------
__global__ __launch_bounds__(256) void conv2_kernel(
    const float* __restrict__ in, const float* __restrict__ w,
    const float* __restrict__ bias, float* __restrict__ out)
{
    const int tile = blockIdx.x;
    const int b = blockIdx.y;
    const int ty = tile / 4, tx = tile % 4;
    const int oh0 = ty * 16, ow0 = tx * 16;

    __shared__ float in_s[4][24][25];
    __shared__ float w_s[16][324];

    const int tid = threadIdx.x;
    const int co = tid / 16;
    const int py = tid % 16;

    float acc[16];
    #pragma unroll
    for (int i = 0; i < 16; ++i) acc[i] = 0.f;

    for (int cc = 0; cc < 8; ++cc) {
        for (int i = tid; i < 4 * 24 * 24; i += 256) {
            int ci = i / 576, r = (i / 24) % 24, c = i % 24;
            int ih = oh0 + r, iw = ow0 + c;
            float v = 0.f;
            if (ih < 71 && iw < 71)
                v = in[((b * 32 + cc * 4 + ci) * 71 + ih) * 71 + iw];
            in_s[ci][r][c] = v;
        }
        for (int i = tid; i < 16 * 324; i += 256) {
            int c2 = i / 324, t = i % 324;
            w_s[c2][t] = w[c2 * 2592 + cc * 324 + t];
        }
        __syncthreads();

        #pragma unroll 1
        for (int ci = 0; ci < 4; ++ci) {
            #pragma unroll 1
            for (int kh = 0; kh < 9; ++kh) {
                float rr[24];
                #pragma unroll
                for (int c = 0; c < 24; ++c) rr[c] = in_s[ci][py + kh][c];
                #pragma unroll
                for (int kw = 0; kw < 9; ++kw) {
                    float wv = w_s[co][ci * 81 + kh * 9 + kw];
                    #pragma unroll
                    for (int px = 0; px < 16; ++px)
                        acc[px] += rr[kw + px] * wv;
                }
            }
        }
        __syncthreads();
    }

    const int oh = oh0 + py;
    if (oh < 63) {
        const float bv = bias[co];
        #pragma unroll
        for (int px = 0; px < 16; ++px) {
            int ow = ow0 + px;
            if (ow < 63)
                out[((b * 16 + co) * 63 + oh) * 63 + ow] = fmaxf(acc[px] + bv, 0.f);
        }
    }
}

// ---------------------------------------------------------------------------
// Stages 3-5 v3: locally-connected conv + ReLU  (unchanged from round 3)
// ---------------------------------------------------------------------------
template<int KS, int STRIDE, int HIN, int WIN, int HOUT, int WOUT>
__global__ __launch_bounds__(256, 4) void lc_v3_kernel(
    const float* __restrict__ in, const float* __restrict__ w,
    const float* __restrict__ bias, float* __restrict__ out)
{
    constexpr int K     = 16 * KS * KS;
    constexpr int NPASS = (K + 127) / 128;
    constexpr int KPAD  = NPASS * 128;
    constexpr int HW    = HOUT * WOUT;
    constexpr int CHW   = 16 * HIN * WIN;
    constexpr int ROWF  = 132;

    __shared__ float patch_s[32 * ROWF];
    __shared__ int   base_s[KPAD];

    const int tid = threadIdx.x;
    const int pos = blockIdx.x;
    const int oh = pos / WOUT, ow = pos % WOUT;
    const int posoff = (oh * STRIDE) * WIN + ow * STRIDE;

    for (int k = tid; k < KPAD; k += 256) {
        int v = 0;
        if (k < K) {
            int ci = k / (KS * KS);
            int r  = k - ci * (KS * KS);
            int kh = r / KS, kw = r - kh * KS;
            v = ci * (HIN * WIN) + kh * WIN + kw;
        }
        base_s[k] = v;
    }

    const int kl  = tid & 31;
    const int cog = (tid >> 5) & 3;
    const int bg  = tid >> 7;
    const int b0  = bg * 16;

    const int sb = tid >> 3;
    const int si = (tid & 7) * 16;
    const float* inb = in + sb * CHW + posoff;

    const float* wbase = w + (size_t)pos * 16 * K;

    float acc[16][4];
    #pragma unroll
    for (int i = 0; i < 16; ++i)
        #pragma unroll
        for (int j = 0; j < 4; ++j) acc[i][j] = 0.f;

    #pragma unroll 1
    for (int ps = 0; ps < NPASS; ++ps) {
        const int kb = ps * 128;

        const int kw4 = kb + kl * 4;
        float4 wv[4];
        #pragma unroll
        for (int cj = 0; cj < 4; ++cj) {
            if (kw4 < K)
                wv[cj] = *reinterpret_cast<const float4*>(
                    wbase + (size_t)(cog * 4 + cj) * K + kw4);
            else
                wv[cj] = make_float4(0.f, 0.f, 0.f, 0.f);
        }

        __syncthreads();

        float tmp[16];
        #pragma unroll
        for (int j = 0; j < 16; ++j)
            tmp[j] = inb[base_s[kb + si + j]];
        #pragma unroll
        for (int j4 = 0; j4 < 4; ++j4) {
            *reinterpret_cast<float4*>(&patch_s[sb * ROWF + si + j4 * 4]) =
                make_float4(tmp[j4 * 4], tmp[j4 * 4 + 1],
                            tmp[j4 * 4 + 2], tmp[j4 * 4 + 3]);
        }
        __syncthreads();

        #pragma unroll
        for (int bi = 0; bi < 16; ++bi) {
            float4 pv = *reinterpret_cast<const float4*>(
                &patch_s[(b0 + bi) * ROWF + kl * 4]);
            #pragma unroll
            for (int cj = 0; cj < 4; ++cj) {
                acc[bi][cj] += pv.x * wv[cj].x + pv.y * wv[cj].y
                             + pv.z * wv[cj].z + pv.w * wv[cj].w;
            }
        }
    }

    #pragma unroll
    for (int bi = 0; bi < 16; ++bi)
        #pragma unroll
        for (int cj = 0; cj < 4; ++cj) {
            float v = acc[bi][cj];
            v += __shfl_xor(v, 1);
            v += __shfl_xor(v, 2);
            v += __shfl_xor(v, 4);
            v += __shfl_xor(v, 8);
            v += __shfl_xor(v, 16);
            acc[bi][cj] = v;
        }

    if (kl == 0) {
        float bv[4];
        #pragma unroll
        for (int cj = 0; cj < 4; ++cj)
            bv[cj] = bias[(cog * 4 + cj) * HW + pos];
        #pragma unroll
        for (int bi = 0; bi < 16; ++bi)
            #pragma unroll
            for (int cj = 0; cj < 4; ++cj) {
                int b = b0 + bi, co = cog * 4 + cj;
                out[(b * 16 + co) * HW + pos] = fmaxf(acc[bi][cj] + bv[cj], 0.f);
            }
    }
}

// ---------------------------------------------------------------------------
// Stage 6 v2: FC (32,7056)@(4096,7056)^T. K split 4 ways.  (unchanged)
// ---------------------------------------------------------------------------
__global__ __launch_bounds__(256) void fc_v2_kernel(
    const float* __restrict__ in, const float* __restrict__ w,
    float* __restrict__ part)
{
    constexpr int K  = 7056;
    constexpr int KR = 1764;
    constexpr int KC = 144;
    constexpr int NCH = (KR + KC - 1) / KC;

    __shared__ float4 patch_s[32][40];
    __shared__ float4 w_s[32][37];

    const int tid = threadIdx.x;
    const int b   = tid & 31;
    const int op  = tid >> 5;
    const int swz = (b >> 2) & 7;
    const int oblk = blockIdx.x;
    const int ks   = blockIdx.y;
    const int kbeg = ks * KR;
    const int klim = kbeg + KR;

    float acc0 = 0.f, acc1 = 0.f, acc2 = 0.f, acc3 = 0.f;

    for (int ch = 0; ch < NCH; ++ch) {
        const int kb = kbeg + ch * KC;
        __syncthreads();

        for (int i4 = tid; i4 < 32 * 36; i4 += 256) {
            int bb = i4 / 36, x4 = i4 - bb * 36;
            int k = kb + x4 * 4;
            float4 v = make_float4(0.f, 0.f, 0.f, 0.f);
            if (k < klim)
                v = *reinterpret_cast<const float4*>(in + bb * K + k);
            patch_s[bb][x4 ^ ((bb >> 2) & 7)] = v;
        }
        for (int i4 = tid; i4 < 32 * 36; i4 += 256) {
            int oi = i4 / 36, x4 = i4 - oi * 36;
            int k = kb + x4 * 4;
            float4 v = make_float4(0.f, 0.f, 0.f, 0.f);
            if (k < klim)
                v = *reinterpret_cast<const float4*>(w + (size_t)(oblk * 32 + oi) * K + k);
            w_s[oi][x4] = v;
        }
        __syncthreads();

        #pragma unroll
        for (int x4 = 0; x4 < 36; ++x4) {
            float4 pv = patch_s[b][x4 ^ swz];
            float4 w0 = w_s[op * 4 + 0][x4];
            float4 w1 = w_s[op * 4 + 1][x4];
            float4 w2 = w_s[op * 4 + 2][x4];
            float4 w3 = w_s[op * 4 + 3][x4];
            acc0 += pv.x * w0.x + pv.y * w0.y + pv.z * w0.z + pv.w * w0.w;
            acc1 += pv.x * w1.x + pv.y * w1.y + pv.z * w1.z + pv.w * w1.w;
            acc2 += pv.x * w2.x + pv.y * w2.y + pv.z * w2.z + pv.w * w2.w;
            acc3 += pv.x * w3.x + pv.y * w3.y + pv.z * w3.z + pv.w * w3.w;
        }
    }

    float4 r = make_float4(acc0, acc1, acc2, acc3);
    *reinterpret_cast<float4*>(part + (size_t)(ks * 32 + b) * 4096 + oblk * 32 + op * 4) = r;
}

__global__ __launch_bounds__(256) void fc_reduce_kernel(
    const float* __restrict__ part, const float* __restrict__ bias,
    float* __restrict__ out)
{
    int i4 = blockIdx.x * 256 + threadIdx.x;
    if (i4 >= 32768) return;
    int b = i4 >> 10, o4 = i4 & 1023;
    const size_t stride = (size_t)32 * 4096;
    const float* base = part + (size_t)b * 4096 + o4 * 4;
    float4 s0 = *reinterpret_cast<const float4*>(base);
    float4 s1 = *reinterpret_cast<const float4*>(base + stride);
    float4 s2 = *reinterpret_cast<const float4*>(base + 2 * stride);
    float4 s3 = *reinterpret_cast<const float4*>(base + 3 * stride);
    float4 bv = *reinterpret_cast<const float4*>(bias + o4 * 4);
    float4 r;
    r.x = s0.x + s1.x + s2.x + s3.x + bv.x;
    r.y = s0.y + s1.y + s2.y + s3.y + bv.y;
    r.z = s0.z + s1.z + s2.z + s3.z + bv.z;
    r.w = s0.w + s1.w + s2.w + s3.w + bv.w;
    *reinterpret_cast<float4*>(out + b * 4096 + o4 * 4) = r;
}

// ---------------------------------------------------------------------------
extern "C" void kernel_launch(void* const* d_in, const int* in_sizes, int n_in,
                              void* d_out, int out_size, void* d_ws, size_t ws_size,
                              hipStream_t stream) {
    const float* x    = (const float*)d_in[0];
    const float* c1w  = (const float*)d_in[1];
    const float* c1b  = (const float*)d_in[2];
    const float* c2w  = (const float*)d_in[3];
    const float* c2b  = (const float*)d_in[4];
    const float* lc1w = (const float*)d_in[5];
    const float* lc1b = (const float*)d_in[6];
    const float* lc2w = (const float*)d_in[7];
    const float* lc2b = (const float*)d_in[8];
    const float* lc3w = (const float*)d_in[9];
    const float* lc3b = (const float*)d_in[10];
    const float* fcw  = (const float*)d_in[11];
    const float* fcb  = (const float*)d_in[12];
    float* out = (float*)d_out;

    float* ws  = (float*)d_ws;
    float* h1p = ws;                 // 32*32*71*71 = 5,161,472
    float* h2  = h1p + 5161472;      // 32*16*63*63 = 2,032,128
    float* h3  = h2  + 2032128;      // 32*16*55*55 = 1,548,800
    float* h4  = h3  + 1548800;      // 32*16*25*25 =   320,000
    float* h5  = h4  + 320000;       // 32*16*21*21 =   225,792
    float* fc_part = h1p;            // conv1 output dead by fc time

    conv1_pool_v2_kernel<<<dim3(25, 4, 32), 256, 0, stream>>>(x, c1w, c1b, h1p);
    conv2_kernel<<<dim3(16, 32), 256, 0, stream>>>(h1p, c2w, c2b, h2);
    lc_v3_kernel<9, 1, 63, 63, 55, 55><<<dim3(55 * 55), 256, 0, stream>>>(h2, lc1w, lc1b, h3);
    lc_v3_kernel<7, 2, 55, 55, 25, 25><<<dim3(25 * 25), 256, 0, stream>>>(h3, lc2w, lc2b, h4);
    lc_v3_kernel<5, 1, 25, 25, 21, 21><<<dim3(21 * 21), 256, 0, stream>>>(h4, lc3w, lc3b, h5);
    fc_v2_kernel<<<dim3(128, 4), 256, 0, stream>>>(h5, fcw, fc_part);
    fc_reduce_kernel<<<dim3(128), 256, 0, stream>>>(fc_part, fcb, out);
}